// Round 11
// baseline (1225.009 us; speedup 1.0000x reference)
//
#include <hip/hip_runtime.h>

#define TT 2048
#define BB 256
#define FF 64
#define HH 128
#define NT 512            // 8 waves; lane = 16*row + 4*p + u
#define RS (BB * FF / 4)  // x row stride in float4

typedef _Float16 h2v __attribute__((ext_vector_type(2)));
typedef _Float16 h4v __attribute__((ext_vector_type(4)));
typedef _Float16 h8v __attribute__((ext_vector_type(8)));

#if __has_builtin(__builtin_amdgcn_rcpf)
#define FRCP(v) __builtin_amdgcn_rcpf(v)
#else
#define FRCP(v) (1.0f / (v))
#endif

__device__ __forceinline__ float fdot2(h2v a, h2v b, float c) {
  return __builtin_amdgcn_fdot2(a, b, c, false);
}
__device__ __forceinline__ int packh2(float a, float b) {
  union { h2v h; int i; } u;
  u.h = h2v{(_Float16)a, (_Float16)b};
  return u.i;
}
__device__ __forceinline__ h2v ash2(int i) { return __builtin_bit_cast(h2v, i); }

// pure-VALU butterfly over the 4 lanes spaced 4 apart within a 16-lane row
template <int CTRL>
__device__ __forceinline__ float dpp_add(float v) {
  int r = __builtin_amdgcn_update_dpp(0, __float_as_int(v), CTRL, 0xF, 0xF, true);
  return v + __int_as_float(r);
}
__device__ __forceinline__ float rowquad_sum(float v) {
  v = dpp_add<0x124>(v);  // row_ror:4
  v = dpp_add<0x128>(v);  // row_ror:8
  return v;
}

// Hot-loop barrier without the vmcnt(0) drain (r9: proven equivalent, kept).
__device__ __forceinline__ void step_barrier() {
  asm volatile("s_waitcnt lgkmcnt(0)" ::: "memory");
  __builtin_amdgcn_s_barrier();
  __builtin_amdgcn_sched_barrier(0);
}

// In-loop pins (proven round 7). Once per 4-step block: the pin->use->next-pin
// dependency chain keeps weights loop-carried in VGPRs across all 4 steps.
#define PINS()                                                             \
  do {                                                                     \
    _Pragma("unroll") for (int _k = 0; _k < 16; ++_k) {                    \
      asm volatile("" : "+v"(whr_i[_k]), "+v"(whz_i[_k]), "+v"(whn_i[_k]));\
    }                                                                      \
    _Pragma("unroll") for (int _k = 0; _k < 8; ++_k) {                     \
      asm volatile("" : "+v"(wxr_i[_k]), "+v"(wxz_i[_k]), "+v"(wxn_i[_k]));\
    }                                                                      \
  } while (0)

__global__ void __launch_bounds__(NT)
__attribute__((amdgpu_waves_per_eu(2, 2)))
gru_scan_kernel(const float* __restrict__ x,     // [T,B,F]
                const float* __restrict__ Wi,    // [F,3H] r|z|n
                const float* __restrict__ bi,    // [3H]
                const float* __restrict__ Whrz,  // [H,2H] r|z
                const float* __restrict__ Whn,   // [H,H]
                const float* __restrict__ bn,    // [H]
                float* __restrict__ out)         // [T,B,H]
{
  const int b    = blockIdx.x;
  const int tid  = threadIdx.x;
  const int w    = tid >> 6;        // wave 0..7
  const int lane = tid & 63;
  const int r16  = (lane >> 4) & 3;
  const int s    = lane & 15;
  const int p    = s >> 2;          // k-part 0..3
  const int u    = s & 3;
  const int g    = w * 16 + r16 * 4 + u;   // hidden unit 0..127

  // f16 operand buffers (matmul inputs only; carried h state stays fp32)
  __shared__ __align__(16) _Float16 h_lds[2][HH];
  __shared__ __align__(16) _Float16 x_lds[4][FF];   // 4-deep ring

  // bank-disjoint chunk schedules (half-element offsets)
  int hoff[4], xoff[2];
  #pragma unroll
  for (int m = 0; m < 4; ++m) hoff[m] = 32 * p + 8 * ((m + (p & 2)) & 3);
  #pragma unroll
  for (int m = 0; m < 2; ++m) xoff[m] = 16 * p + 8 * m;

  // ---- stationary weights: (16+8)*3 = 72 half2-in-int per thread ----
  int whr_i[16], whz_i[16], whn_i[16];
  int wxr_i[8], wxz_i[8], wxn_i[8];
  #pragma unroll
  for (int m = 0; m < 4; ++m) {
    #pragma unroll
    for (int e = 0; e < 4; ++e) {
      const int k = hoff[m] + 2 * e;   // k, k+1 in 0..127
      whr_i[4 * m + e]  = packh2(Whrz[(size_t)k * 256 + g],
                                 Whrz[(size_t)(k + 1) * 256 + g]);
      whz_i[4 * m + e]  = packh2(Whrz[(size_t)k * 256 + 128 + g],
                                 Whrz[(size_t)(k + 1) * 256 + 128 + g]);
      whn_i[4 * m + e]  = packh2(Whn[(size_t)k * 128 + g],
                                 Whn[(size_t)(k + 1) * 128 + g]);
    }
  }
  #pragma unroll
  for (int m = 0; m < 2; ++m) {
    #pragma unroll
    for (int e = 0; e < 4; ++e) {
      const int k = xoff[m] + 2 * e;   // k, k+1 in 0..63
      wxr_i[4 * m + e] = packh2(Wi[(size_t)k * 384 + g],
                                Wi[(size_t)(k + 1) * 384 + g]);
      wxz_i[4 * m + e] = packh2(Wi[(size_t)k * 384 + 128 + g],
                                Wi[(size_t)(k + 1) * 384 + 128 + g]);
      wxn_i[4 * m + e] = packh2(Wi[(size_t)k * 384 + 256 + g],
                                Wi[(size_t)(k + 1) * 384 + 256 + g]);
    }
  }
  const float b_r  = (p == 0) ? bi[g]       : 0.0f;
  const float b_z  = (p == 0) ? bi[128 + g] : 0.0f;
  const float b_xn = (p == 0) ? bi[256 + g] : 0.0f;
  const float b_hn = (p == 0) ? bn[g]       : 0.0f;

  // x-dot on x_lds slot S, accumulating into the pipeline regs
#define XDOT(S, DR, DZ, DN)                                                 \
  {                                                                         \
    const _Float16* xb_ = x_lds[(S)];                                       \
    DR = b_r; DZ = b_z; DN = b_xn;                                          \
    _Pragma("unroll")                                                       \
    for (int m = 0; m < 2; ++m) {                                           \
      const h8v v = *(const h8v*)(xb_ + xoff[m]);                           \
      const h2v v0 = h2v{v.s0, v.s1}, v1 = h2v{v.s2, v.s3};                 \
      const h2v v2 = h2v{v.s4, v.s5}, v3 = h2v{v.s6, v.s7};                 \
      DR = fdot2(v0, ash2(wxr_i[4 * m + 0]), DR);                           \
      DR = fdot2(v1, ash2(wxr_i[4 * m + 1]), DR);                           \
      DR = fdot2(v2, ash2(wxr_i[4 * m + 2]), DR);                           \
      DR = fdot2(v3, ash2(wxr_i[4 * m + 3]), DR);                           \
      DZ = fdot2(v0, ash2(wxz_i[4 * m + 0]), DZ);                           \
      DZ = fdot2(v1, ash2(wxz_i[4 * m + 1]), DZ);                           \
      DZ = fdot2(v2, ash2(wxz_i[4 * m + 2]), DZ);                           \
      DZ = fdot2(v3, ash2(wxz_i[4 * m + 3]), DZ);                           \
      DN = fdot2(v0, ash2(wxn_i[4 * m + 0]), DN);                           \
      DN = fdot2(v1, ash2(wxn_i[4 * m + 1]), DN);                           \
      DN = fdot2(v2, ash2(wxn_i[4 * m + 2]), DN);                           \
      DN = fdot2(v3, ash2(wxn_i[4 * m + 3]), DN);                           \
    }                                                                       \
  }

  // ---- init: h=0; stage x[0]->slot0, x[1]->slot1; prefetch x[2..5] ----
  if (tid < HH) h_lds[0][tid] = (_Float16)0.0f;
  if (tid < 32) {
    const int slot = tid >> 4;   // 0 or 1
    const int i4   = tid & 15;
    const float4 v = ((const float4*)(x + (size_t)slot * BB * FF +
                                      (size_t)b * FF))[i4];
    *(h4v*)&x_lds[slot][4 * i4] =
        h4v{(_Float16)v.x, (_Float16)v.y, (_Float16)v.z, (_Float16)v.w};
  }
  const bool loader = (tid >= NT - 16);   // wave 7, lanes 48..63
  const int  lidx   = tid & 15;
  const float4* xsrc = (const float4*)(x + ((size_t)2 * BB + b) * FF) + lidx;
  float4 xv0, xv1, xv2, xv3;
  if (loader) {
    xv0 = xsrc[0 * (size_t)RS];   // x[2]
    xv1 = xsrc[1 * (size_t)RS];   // x[3]
    xv2 = xsrc[2 * (size_t)RS];   // x[4]
    xv3 = xsrc[3 * (size_t)RS];   // x[5]
    xsrc += 4 * (size_t)RS;       // -> x[6]
  }
  float* outp = out + (size_t)b * HH + g;
  float h_old = 0.0f;
  float pxr, pxz, pxn;            // x-partials pipeline (for the CURRENT step)
  __syncthreads();                // x[0], x[1] visible
  XDOT(0, pxr, pxz, pxn)          // partials for t=0

  // STEP(P): consumes pxr/pxz/pxn (for step t), computes them for t+1 from
  // slot (P+1)&3 (written during step t-1, barrier-separated). Loader writes
  // x[t+2] into slot (P+2)&3 and refills XV with x[t+6].
#define STEP(P, XV)                                                         \
  {                                                                         \
    const int t_ = tbase + (P);                                             \
    if (loader) {                                                           \
      *(h4v*)&x_lds[((P) + 2) & 3][4 * lidx] =                              \
          h4v{(_Float16)XV.x, (_Float16)XV.y, (_Float16)XV.z,               \
              (_Float16)XV.w};                               /* x[t+2] */   \
      if (t_ + 6 < TT) { XV = *xsrc; xsrc += RS; }           /* x[t+6] */   \
    }                                                                       \
    const _Float16* hb = h_lds[(P) & 1];                                    \
    const float cxr = pxr, cxz = pxz, cxn = pxn;                            \
    float ahr0 = 0.f, ahr1 = 0.f, ahr2 = 0.f, ahr3 = 0.f;                   \
    float ahz0 = 0.f, ahz1 = 0.f, ahz2 = 0.f, ahz3 = 0.f;                   \
    float ahn0 = b_hn, ahn1 = 0.f, ahn2 = 0.f, ahn3 = 0.f;                  \
    _Pragma("unroll")                                                       \
    for (int m = 0; m < 4; ++m) {                                           \
      const h8v v = *(const h8v*)(hb + hoff[m]);                            \
      const h2v v0 = h2v{v.s0, v.s1}, v1 = h2v{v.s2, v.s3};                 \
      const h2v v2 = h2v{v.s4, v.s5}, v3 = h2v{v.s6, v.s7};                 \
      float& br = (m == 0) ? ahr0 : (m == 1) ? ahr1 : (m == 2) ? ahr2 : ahr3; \
      float& bz = (m == 0) ? ahz0 : (m == 1) ? ahz1 : (m == 2) ? ahz2 : ahz3; \
      float& bq = (m == 0) ? ahn0 : (m == 1) ? ahn1 : (m == 2) ? ahn2 : ahn3; \
      br = fdot2(v0, ash2(whr_i[4 * m + 0]), br);                           \
      br = fdot2(v1, ash2(whr_i[4 * m + 1]), br);                           \
      br = fdot2(v2, ash2(whr_i[4 * m + 2]), br);                           \
      br = fdot2(v3, ash2(whr_i[4 * m + 3]), br);                           \
      bz = fdot2(v0, ash2(whz_i[4 * m + 0]), bz);                           \
      bz = fdot2(v1, ash2(whz_i[4 * m + 1]), bz);                           \
      bz = fdot2(v2, ash2(whz_i[4 * m + 2]), bz);                           \
      bz = fdot2(v3, ash2(whz_i[4 * m + 3]), bz);                           \
      bq = fdot2(v0, ash2(whn_i[4 * m + 0]), bq);                           \
      bq = fdot2(v1, ash2(whn_i[4 * m + 1]), bq);                           \
      bq = fdot2(v2, ash2(whn_i[4 * m + 2]), bq);                           \
      bq = fdot2(v3, ash2(whn_i[4 * m + 3]), bq);                           \
    }                                                                       \
    float pr = rowquad_sum(cxr + ((ahr0 + ahr1) + (ahr2 + ahr3)));          \
    float pz = rowquad_sum(cxz + ((ahz0 + ahz1) + (ahz2 + ahz3)));          \
    float xnv = rowquad_sum(cxn);                                           \
    float hnv = rowquad_sum((ahn0 + ahn1) + (ahn2 + ahn3));                 \
    /* x-dot for t+1: independent of h -> fills reduce/exp-tail bubbles */  \
    XDOT(((P) + 1) & 3, pxr, pxz, pxn)                                      \
    const float rg = FRCP(1.0f + __expf(-pr));                              \
    const float zg = FRCP(1.0f + __expf(-pz));                              \
    const float na = xnv + rg * hnv;                                        \
    const float ng = 1.0f - 2.0f * FRCP(__expf(2.0f * na) + 1.0f);          \
    const float hnew = zg * (h_old - ng) + ng;                              \
    h_old = hnew;                                                           \
    if (p == 0) {                                                           \
      h_lds[((P) + 1) & 1][g] = (_Float16)hnew;                             \
      *outp = hnew;                                                         \
    }                                                                       \
    outp += BB * HH;                                                        \
    step_barrier();                                                         \
  }

  for (int tbase = 0; tbase < TT; tbase += 4) {
    PINS();
    STEP(0, xv0)
    STEP(1, xv1)
    STEP(2, xv2)
    STEP(3, xv3)
  }
#undef STEP
#undef XDOT
}

extern "C" void kernel_launch(void* const* d_in, const int* in_sizes, int n_in,
                              void* d_out, int out_size, void* d_ws, size_t ws_size,
                              hipStream_t stream) {
  const float* x    = (const float*)d_in[0];
  const float* Wi   = (const float*)d_in[1];
  const float* bi   = (const float*)d_in[2];
  const float* Whrz = (const float*)d_in[3];
  const float* Whn  = (const float*)d_in[4];
  const float* bn   = (const float*)d_in[5];
  float* out = (float*)d_out;

  gru_scan_kernel<<<dim3(BB), dim3(NT), 0, stream>>>(
      x, Wi, bi, Whrz, Whn, bn, out);
}

// Round 12
// 1188.211 us; speedup vs baseline: 1.0310x; 1.0310x over previous
//
#include <hip/hip_runtime.h>

#define TT 2048
#define BB 256
#define FF 64
#define HH 128
#define NT 256            // 4 waves, 1 wave/SIMD; lane = 2*(unit-in-wave) + p
#define RS (BB * FF / 4)  // x row stride in float4

typedef _Float16 h2v __attribute__((ext_vector_type(2)));
typedef _Float16 h4v __attribute__((ext_vector_type(4)));
typedef _Float16 h8v __attribute__((ext_vector_type(8)));

#if __has_builtin(__builtin_amdgcn_rcpf)
#define FRCP(v) __builtin_amdgcn_rcpf(v)
#else
#define FRCP(v) (1.0f / (v))
#endif

__device__ __forceinline__ float fdot2(h2v a, h2v b, float c) {
  return __builtin_amdgcn_fdot2(a, b, c, false);
}
__device__ __forceinline__ int packh2(float a, float b) {
  union { h2v h; int i; } u;
  u.h = h2v{(_Float16)a, (_Float16)b};
  return u.i;
}
__device__ __forceinline__ h2v ash2(int i) { return __builtin_bit_cast(h2v, i); }

// 1-hop pair reduce: DPP quad_perm [1,0,3,2] (lane 2k <-> 2k+1), pure VALU
__device__ __forceinline__ float pair_sum(float v) {
  int r = __builtin_amdgcn_update_dpp(0, __float_as_int(v), 0xB1, 0xF, 0xF, true);
  return v + __int_as_float(r);
}

// Hot-loop barrier without the vmcnt(0) drain (r9: proven equivalent).
__device__ __forceinline__ void step_barrier() {
  asm volatile("s_waitcnt lgkmcnt(0)" ::: "memory");
  __builtin_amdgcn_s_barrier();
  __builtin_amdgcn_sched_barrier(0);
}

// In-loop pins (proven r7): reload-from-memory is an illegal materialization,
// weights stay loop-carried in VGPRs. 144 packed ints = 288 f16 weights.
#define PINS()                                                             \
  do {                                                                     \
    _Pragma("unroll") for (int _k = 0; _k < 32; ++_k) {                    \
      asm volatile("" : "+v"(whr_i[_k]), "+v"(whz_i[_k]), "+v"(whn_i[_k]));\
    }                                                                      \
    _Pragma("unroll") for (int _k = 0; _k < 16; ++_k) {                    \
      asm volatile("" : "+v"(wxr_i[_k]), "+v"(wxz_i[_k]), "+v"(wxn_i[_k]));\
    }                                                                      \
  } while (0)

__global__ void __launch_bounds__(NT)
__attribute__((amdgpu_waves_per_eu(1, 1)))
gru_scan_kernel(const float* __restrict__ x,     // [T,B,F]
                const float* __restrict__ Wi,    // [F,3H] r|z|n
                const float* __restrict__ bi,    // [3H]
                const float* __restrict__ Whrz,  // [H,2H] r|z
                const float* __restrict__ Whn,   // [H,H]
                const float* __restrict__ bn,    // [H]
                float* __restrict__ out)         // [T,B,H]
{
  const int b    = blockIdx.x;
  const int tid  = threadIdx.x;
  const int w    = tid >> 6;        // wave 0..3
  const int lane = tid & 63;
  const int p    = lane & 1;        // k-half 0/1
  const int g    = w * 32 + (lane >> 1);   // hidden unit 0..127

  // f16 operand buffers (matmul inputs only; carried h state stays fp32)
  __shared__ __align__(16) _Float16 h_lds[2][HH];
  __shared__ __align__(16) _Float16 x_lds[4][FF];   // 4-deep ring

  // bank-disjoint chunk schedules (half-element offsets):
  // h: p0 bytes 16m, p1 bytes 128+16((m+4)&7) -> always 64B apart mod 128.
  // x: p0 bytes 16m, p1 bytes 64+16((m+2)&3)  -> disjoint quads.
  int hoff[8], xoff[4];
  #pragma unroll
  for (int m = 0; m < 8; ++m) hoff[m] = 64 * p + 8 * ((m + 4 * p) & 7);
  #pragma unroll
  for (int m = 0; m < 4; ++m) xoff[m] = 32 * p + 8 * ((m + 2 * p) & 3);

  // ---- stationary weights: (32+16)*3 = 144 half2-in-int per thread ----
  int whr_i[32], whz_i[32], whn_i[32];
  int wxr_i[16], wxz_i[16], wxn_i[16];
  #pragma unroll
  for (int m = 0; m < 8; ++m) {
    #pragma unroll
    for (int e = 0; e < 4; ++e) {
      const int k = hoff[m] + 2 * e;   // k, k+1 in 0..127
      whr_i[4 * m + e] = packh2(Whrz[(size_t)k * 256 + g],
                                Whrz[(size_t)(k + 1) * 256 + g]);
      whz_i[4 * m + e] = packh2(Whrz[(size_t)k * 256 + 128 + g],
                                Whrz[(size_t)(k + 1) * 256 + 128 + g]);
      whn_i[4 * m + e] = packh2(Whn[(size_t)k * 128 + g],
                                Whn[(size_t)(k + 1) * 128 + g]);
    }
  }
  #pragma unroll
  for (int m = 0; m < 4; ++m) {
    #pragma unroll
    for (int e = 0; e < 4; ++e) {
      const int k = xoff[m] + 2 * e;   // k, k+1 in 0..63
      wxr_i[4 * m + e] = packh2(Wi[(size_t)k * 384 + g],
                                Wi[(size_t)(k + 1) * 384 + g]);
      wxz_i[4 * m + e] = packh2(Wi[(size_t)k * 384 + 128 + g],
                                Wi[(size_t)(k + 1) * 384 + 128 + g]);
      wxn_i[4 * m + e] = packh2(Wi[(size_t)k * 384 + 256 + g],
                                Wi[(size_t)(k + 1) * 384 + 256 + g]);
    }
  }
  const float b_r  = (p == 0) ? bi[g]       : 0.0f;
  const float b_z  = (p == 0) ? bi[128 + g] : 0.0f;
  const float b_xn = (p == 0) ? bi[256 + g] : 0.0f;
  const float b_hn = (p == 0) ? bn[g]       : 0.0f;

  // ---- init: h=0; x[0]->slot0, x[1]->slot1; prefetch x[2..5] ----
  if (tid < HH) h_lds[0][tid] = (_Float16)0.0f;
  if (tid < 32) {
    const int slot = tid >> 4;   // 0 or 1
    const int i4   = tid & 15;
    const float4 v = ((const float4*)(x + (size_t)slot * BB * FF +
                                      (size_t)b * FF))[i4];
    *(h4v*)&x_lds[slot][4 * i4] =
        h4v{(_Float16)v.x, (_Float16)v.y, (_Float16)v.z, (_Float16)v.w};
  }
  const bool loader = (tid >= NT - 16);   // wave 3, lanes 48..63
  const int  lidx   = tid & 15;
  const float4* xsrc = (const float4*)(x + ((size_t)2 * BB + b) * FF) + lidx;
  float4 xv0, xv1, xv2, xv3;
  if (loader) {
    xv0 = xsrc[0 * (size_t)RS];   // x[2]
    xv1 = xsrc[1 * (size_t)RS];   // x[3]
    xv2 = xsrc[2 * (size_t)RS];   // x[4]
    xv3 = xsrc[3 * (size_t)RS];   // x[5]
    xsrc += 4 * (size_t)RS;       // -> x[6]
  }
  float* outp = out + (size_t)b * HH + g;
  float h_old = 0.0f;
  __syncthreads();

  // STEP(P): x[t] lives in slot P&3 (staged at step t-2). Loader writes
  // x[t+2] into slot (P+2)&3 (its old content x[t-2] was last read at step
  // t-2, barrier-separated) and refills XV with x[t+6].
#define STEP(P, XV)                                                         \
  {                                                                         \
    const int t_ = tbase + (P);                                             \
    if (loader) {                                                           \
      *(h4v*)&x_lds[((P) + 2) & 3][4 * lidx] =                              \
          h4v{(_Float16)XV.x, (_Float16)XV.y, (_Float16)XV.z,               \
              (_Float16)XV.w};                               /* x[t+2] */   \
      if (t_ + 6 < TT) { XV = *xsrc; xsrc += RS; }           /* x[t+6] */   \
    }                                                                       \
    const _Float16* xb = x_lds[(P) & 3];                                    \
    const _Float16* hb = h_lds[(P) & 1];                                    \
    /* x-dot: 16 k's -> 48 dot2, 2 accs/gate (depth 8) */                   \
    float axr0 = b_r, axz0 = b_z, axn0 = b_xn;                              \
    float axr1 = 0.f, axz1 = 0.f, axn1 = 0.f;                               \
    _Pragma("unroll")                                                       \
    for (int m = 0; m < 4; ++m) {                                           \
      const h8v v = *(const h8v*)(xb + xoff[m]);                            \
      const h2v v0 = h2v{v.s0, v.s1}, v1 = h2v{v.s2, v.s3};                 \
      const h2v v2 = h2v{v.s4, v.s5}, v3 = h2v{v.s6, v.s7};                 \
      float& ar = (m & 1) ? axr1 : axr0;                                    \
      float& az = (m & 1) ? axz1 : axz0;                                    \
      float& an = (m & 1) ? axn1 : axn0;                                    \
      ar = fdot2(v0, ash2(wxr_i[4 * m + 0]), ar);                           \
      ar = fdot2(v1, ash2(wxr_i[4 * m + 1]), ar);                           \
      ar = fdot2(v2, ash2(wxr_i[4 * m + 2]), ar);                           \
      ar = fdot2(v3, ash2(wxr_i[4 * m + 3]), ar);                           \
      az = fdot2(v0, ash2(wxz_i[4 * m + 0]), az);                           \
      az = fdot2(v1, ash2(wxz_i[4 * m + 1]), az);                           \
      az = fdot2(v2, ash2(wxz_i[4 * m + 2]), az);                           \
      az = fdot2(v3, ash2(wxz_i[4 * m + 3]), az);                           \
      an = fdot2(v0, ash2(wxn_i[4 * m + 0]), an);                           \
      an = fdot2(v1, ash2(wxn_i[4 * m + 1]), an);                           \
      an = fdot2(v2, ash2(wxn_i[4 * m + 2]), an);                           \
      an = fdot2(v3, ash2(wxn_i[4 * m + 3]), an);                           \
    }                                                                       \
    /* h-dot: 64 k's -> 96 dot2, 4 accs/gate (depth 8) */                   \
    float ahr0 = 0.f, ahr1 = 0.f, ahr2 = 0.f, ahr3 = 0.f;                   \
    float ahz0 = 0.f, ahz1 = 0.f, ahz2 = 0.f, ahz3 = 0.f;                   \
    float ahn0 = b_hn, ahn1 = 0.f, ahn2 = 0.f, ahn3 = 0.f;                  \
    _Pragma("unroll")                                                       \
    for (int m = 0; m < 8; ++m) {                                           \
      const h8v v = *(const h8v*)(hb + hoff[m]);                            \
      const h2v v0 = h2v{v.s0, v.s1}, v1 = h2v{v.s2, v.s3};                 \
      const h2v v2 = h2v{v.s4, v.s5}, v3 = h2v{v.s6, v.s7};                 \
      float& br = (m & 3) == 0 ? ahr0 : (m & 3) == 1 ? ahr1                 \
                : (m & 3) == 2 ? ahr2 : ahr3;                               \
      float& bz = (m & 3) == 0 ? ahz0 : (m & 3) == 1 ? ahz1                 \
                : (m & 3) == 2 ? ahz2 : ahz3;                               \
      float& bq = (m & 3) == 0 ? ahn0 : (m & 3) == 1 ? ahn1                 \
                : (m & 3) == 2 ? ahn2 : ahn3;                               \
      br = fdot2(v0, ash2(whr_i[4 * m + 0]), br);                           \
      br = fdot2(v1, ash2(whr_i[4 * m + 1]), br);                           \
      br = fdot2(v2, ash2(whr_i[4 * m + 2]), br);                           \
      br = fdot2(v3, ash2(whr_i[4 * m + 3]), br);                           \
      bz = fdot2(v0, ash2(whz_i[4 * m + 0]), bz);                           \
      bz = fdot2(v1, ash2(whz_i[4 * m + 1]), bz);                           \
      bz = fdot2(v2, ash2(whz_i[4 * m + 2]), bz);                           \
      bz = fdot2(v3, ash2(whz_i[4 * m + 3]), bz);                           \
      bq = fdot2(v0, ash2(whn_i[4 * m + 0]), bq);                           \
      bq = fdot2(v1, ash2(whn_i[4 * m + 1]), bq);                           \
      bq = fdot2(v2, ash2(whn_i[4 * m + 2]), bq);                           \
      bq = fdot2(v3, ash2(whn_i[4 * m + 3]), bq);                           \
    }                                                                       \
    /* 1-hop pair reduce (DPP), then gate tail */                           \
    float pr = pair_sum((axr0 + axr1) + ((ahr0 + ahr1) + (ahr2 + ahr3)));   \
    float pz = pair_sum((axz0 + axz1) + ((ahz0 + ahz1) + (ahz2 + ahz3)));   \
    float xnv = pair_sum(axn0 + axn1);                                      \
    float hnv = pair_sum((ahn0 + ahn1) + (ahn2 + ahn3));                    \
    const float rg = FRCP(1.0f + __expf(-pr));                              \
    const float zg = FRCP(1.0f + __expf(-pz));                              \
    const float na = xnv + rg * hnv;                                        \
    const float ng = 1.0f - 2.0f * FRCP(__expf(2.0f * na) + 1.0f);          \
    const float hnew = zg * (h_old - ng) + ng;                              \
    h_old = hnew;                                                           \
    if (p == 0) {                                                           \
      h_lds[((P) + 1) & 1][g] = (_Float16)hnew;                             \
      *outp = hnew;                                                         \
    }                                                                       \
    outp += BB * HH;                                                        \
    step_barrier();                                                         \
  }

  for (int tbase = 0; tbase < TT; tbase += 4) {
    PINS();
    STEP(0, xv0)
    STEP(1, xv1)
    STEP(2, xv2)
    STEP(3, xv3)
  }
#undef STEP
}

extern "C" void kernel_launch(void* const* d_in, const int* in_sizes, int n_in,
                              void* d_out, int out_size, void* d_ws, size_t ws_size,
                              hipStream_t stream) {
  const float* x    = (const float*)d_in[0];
  const float* Wi   = (const float*)d_in[1];
  const float* bi   = (const float*)d_in[2];
  const float* Whrz = (const float*)d_in[3];
  const float* Whn  = (const float*)d_in[4];
  const float* bn   = (const float*)d_in[5];
  float* out = (float*)d_out;

  gru_scan_kernel<<<dim3(BB), dim3(NT), 0, stream>>>(
      x, Wi, bi, Whrz, Whn, bn, out);
}

// Round 13
// 1169.484 us; speedup vs baseline: 1.0475x; 1.0160x over previous
//
#include <hip/hip_runtime.h>

#define TT 2048
#define BB 256
#define FF 64
#define HH 128
#define NT 256            // 4 waves, 1 wave/SIMD; lane = 2*(unit-in-wave) + p
#define RS (BB * FF / 4)  // x row stride in float4

typedef _Float16 h2v __attribute__((ext_vector_type(2)));
typedef _Float16 h4v __attribute__((ext_vector_type(4)));
typedef _Float16 h8v __attribute__((ext_vector_type(8)));

#if __has_builtin(__builtin_amdgcn_rcpf)
#define FRCP(v) __builtin_amdgcn_rcpf(v)
#else
#define FRCP(v) (1.0f / (v))
#endif

__device__ __forceinline__ float fdot2(h2v a, h2v b, float c) {
  return __builtin_amdgcn_fdot2(a, b, c, false);
}
__device__ __forceinline__ int packh2(float a, float b) {
  union { h2v h; int i; } u;
  u.h = h2v{(_Float16)a, (_Float16)b};
  return u.i;
}
__device__ __forceinline__ h2v ash2(int i) { return __builtin_bit_cast(h2v, i); }

// 1-hop pair reduce: DPP quad_perm [1,0,3,2] (lane 2k <-> 2k+1), pure VALU
__device__ __forceinline__ float pair_sum(float v) {
  int r = __builtin_amdgcn_update_dpp(0, __float_as_int(v), 0xB1, 0xF, 0xF, true);
  return v + __int_as_float(r);
}

// Hot-loop barrier without the vmcnt(0) drain (r9: proven equivalent).
__device__ __forceinline__ void step_barrier() {
  asm volatile("s_waitcnt lgkmcnt(0)" ::: "memory");
  __builtin_amdgcn_s_barrier();
  __builtin_amdgcn_sched_barrier(0);
}

// In-loop pins (proven r7): reload-from-memory is an illegal materialization,
// weights stay loop-carried in VGPRs. 144 packed ints = 288 f16 weights.
#define PINS()                                                             \
  do {                                                                     \
    _Pragma("unroll") for (int _k = 0; _k < 32; ++_k) {                    \
      asm volatile("" : "+v"(whr_i[_k]), "+v"(whz_i[_k]), "+v"(whn_i[_k]));\
    }                                                                      \
    _Pragma("unroll") for (int _k = 0; _k < 16; ++_k) {                    \
      asm volatile("" : "+v"(wxr_i[_k]), "+v"(wxz_i[_k]), "+v"(wxn_i[_k]));\
    }                                                                      \
  } while (0)

__global__ void __launch_bounds__(NT)
__attribute__((amdgpu_waves_per_eu(1, 1)))
gru_scan_kernel(const float* __restrict__ x,     // [T,B,F]
                const float* __restrict__ Wi,    // [F,3H] r|z|n
                const float* __restrict__ bi,    // [3H]
                const float* __restrict__ Whrz,  // [H,2H] r|z
                const float* __restrict__ Whn,   // [H,H]
                const float* __restrict__ bn,    // [H]
                float* __restrict__ out)         // [T,B,H]
{
  const int b    = blockIdx.x;
  const int tid  = threadIdx.x;
  const int w    = tid >> 6;        // wave 0..3
  const int lane = tid & 63;
  const int p    = lane & 1;        // k-half 0/1
  const int g    = w * 32 + (lane >> 1);   // hidden unit 0..127

  // f16 operand buffers (matmul inputs only; carried h state stays fp32)
  __shared__ __align__(16) _Float16 h_lds[2][HH];
  __shared__ __align__(16) _Float16 x_lds[4][FF];   // 4-deep ring

  // bank-disjoint chunk schedules (half-element offsets)
  int hoff[8], xoff[4];
  #pragma unroll
  for (int m = 0; m < 8; ++m) hoff[m] = 64 * p + 8 * ((m + 4 * p) & 7);
  #pragma unroll
  for (int m = 0; m < 4; ++m) xoff[m] = 32 * p + 8 * ((m + 2 * p) & 3);

  // ---- stationary weights: (32+16)*3 = 144 half2-in-int per thread ----
  int whr_i[32], whz_i[32], whn_i[32];
  int wxr_i[16], wxz_i[16], wxn_i[16];
  #pragma unroll
  for (int m = 0; m < 8; ++m) {
    #pragma unroll
    for (int e = 0; e < 4; ++e) {
      const int k = hoff[m] + 2 * e;   // k, k+1 in 0..127
      whr_i[4 * m + e] = packh2(Whrz[(size_t)k * 256 + g],
                                Whrz[(size_t)(k + 1) * 256 + g]);
      whz_i[4 * m + e] = packh2(Whrz[(size_t)k * 256 + 128 + g],
                                Whrz[(size_t)(k + 1) * 256 + 128 + g]);
      whn_i[4 * m + e] = packh2(Whn[(size_t)k * 128 + g],
                                Whn[(size_t)(k + 1) * 128 + g]);
    }
  }
  #pragma unroll
  for (int m = 0; m < 4; ++m) {
    #pragma unroll
    for (int e = 0; e < 4; ++e) {
      const int k = xoff[m] + 2 * e;   // k, k+1 in 0..63
      wxr_i[4 * m + e] = packh2(Wi[(size_t)k * 384 + g],
                                Wi[(size_t)(k + 1) * 384 + g]);
      wxz_i[4 * m + e] = packh2(Wi[(size_t)k * 384 + 128 + g],
                                Wi[(size_t)(k + 1) * 384 + 128 + g]);
      wxn_i[4 * m + e] = packh2(Wi[(size_t)k * 384 + 256 + g],
                                Wi[(size_t)(k + 1) * 384 + 256 + g]);
    }
  }
  const float b_r  = (p == 0) ? bi[g]       : 0.0f;
  const float b_z  = (p == 0) ? bi[128 + g] : 0.0f;
  const float b_xn = (p == 0) ? bi[256 + g] : 0.0f;
  const float b_hn = (p == 0) ? bn[g]       : 0.0f;

  // x-dot on x_lds slot S -> fresh partials (2 accs/gate, merged at the end)
#define XDOT(S, DR, DZ, DN)                                                 \
  {                                                                         \
    const _Float16* xb_ = x_lds[(S)];                                       \
    float dr0 = b_r, dz0 = b_z, dn0 = b_xn;                                 \
    float dr1 = 0.f, dz1 = 0.f, dn1 = 0.f;                                  \
    _Pragma("unroll")                                                       \
    for (int m = 0; m < 4; ++m) {                                           \
      const h8v v = *(const h8v*)(xb_ + xoff[m]);                           \
      const h2v v0 = h2v{v.s0, v.s1}, v1 = h2v{v.s2, v.s3};                 \
      const h2v v2 = h2v{v.s4, v.s5}, v3 = h2v{v.s6, v.s7};                 \
      float& ar = (m & 1) ? dr1 : dr0;                                      \
      float& az = (m & 1) ? dz1 : dz0;                                      \
      float& an = (m & 1) ? dn1 : dn0;                                      \
      ar = fdot2(v0, ash2(wxr_i[4 * m + 0]), ar);                           \
      ar = fdot2(v1, ash2(wxr_i[4 * m + 1]), ar);                           \
      ar = fdot2(v2, ash2(wxr_i[4 * m + 2]), ar);                           \
      ar = fdot2(v3, ash2(wxr_i[4 * m + 3]), ar);                           \
      az = fdot2(v0, ash2(wxz_i[4 * m + 0]), az);                           \
      az = fdot2(v1, ash2(wxz_i[4 * m + 1]), az);                           \
      az = fdot2(v2, ash2(wxz_i[4 * m + 2]), az);                           \
      az = fdot2(v3, ash2(wxz_i[4 * m + 3]), az);                           \
      an = fdot2(v0, ash2(wxn_i[4 * m + 0]), an);                           \
      an = fdot2(v1, ash2(wxn_i[4 * m + 1]), an);                           \
      an = fdot2(v2, ash2(wxn_i[4 * m + 2]), an);                           \
      an = fdot2(v3, ash2(wxn_i[4 * m + 3]), an);                           \
    }                                                                       \
    DR = dr0 + dr1; DZ = dz0 + dz1; DN = dn0 + dn1;                         \
  }

  // ---- init: h=0; x[0]->slot0, x[1]->slot1; prefetch x[2..5] ----
  if (tid < HH) h_lds[0][tid] = (_Float16)0.0f;
  if (tid < 32) {
    const int slot = tid >> 4;   // 0 or 1
    const int i4   = tid & 15;
    const float4 v = ((const float4*)(x + (size_t)slot * BB * FF +
                                      (size_t)b * FF))[i4];
    *(h4v*)&x_lds[slot][4 * i4] =
        h4v{(_Float16)v.x, (_Float16)v.y, (_Float16)v.z, (_Float16)v.w};
  }
  const bool loader = (tid >= NT - 16);   // wave 3, lanes 48..63
  const int  lidx   = tid & 15;
  const float4* xsrc = (const float4*)(x + ((size_t)2 * BB + b) * FF) + lidx;
  float4 xv0, xv1, xv2, xv3;
  if (loader) {
    xv0 = xsrc[0 * (size_t)RS];   // x[2]
    xv1 = xsrc[1 * (size_t)RS];   // x[3]
    xv2 = xsrc[2 * (size_t)RS];   // x[4]
    xv3 = xsrc[3 * (size_t)RS];   // x[5]
    xsrc += 4 * (size_t)RS;       // -> x[6]
  }
  float* outp = out + (size_t)b * HH + g;
  float h_old = 0.0f;
  float pxr, pxz, pxn;            // x-partials pipeline (for the CURRENT step)
  __syncthreads();                // x[0], x[1] visible
  XDOT(0, pxr, pxz, pxn)          // partials for t=0

  // STEP(P): consumes pxr/pxz/pxn for step t; computes them for t+1 from slot
  // (P+1)&3 (written at step t-1, barrier-separated) -- the independent work
  // that fills the gate-tail/write/barrier stall window at 1 wave/SIMD.
  // Loader writes x[t+2] into slot (P+2)&3 and refills XV with x[t+6].
#define STEP(P, XV)                                                         \
  {                                                                         \
    const int t_ = tbase + (P);                                             \
    if (loader) {                                                           \
      *(h4v*)&x_lds[((P) + 2) & 3][4 * lidx] =                              \
          h4v{(_Float16)XV.x, (_Float16)XV.y, (_Float16)XV.z,               \
              (_Float16)XV.w};                               /* x[t+2] */   \
      if (t_ + 6 < TT) { XV = *xsrc; xsrc += RS; }           /* x[t+6] */   \
    }                                                                       \
    const _Float16* hb = h_lds[(P) & 1];                                    \
    const float cxr = pxr, cxz = pxz, cxn = pxn;                            \
    /* h-dot: 64 k's -> 96 dot2, 4 accs/gate (depth 8) */                   \
    float ahr0 = 0.f, ahr1 = 0.f, ahr2 = 0.f, ahr3 = 0.f;                   \
    float ahz0 = 0.f, ahz1 = 0.f, ahz2 = 0.f, ahz3 = 0.f;                   \
    float ahn0 = b_hn, ahn1 = 0.f, ahn2 = 0.f, ahn3 = 0.f;                  \
    _Pragma("unroll")                                                       \
    for (int m = 0; m < 8; ++m) {                                           \
      const h8v v = *(const h8v*)(hb + hoff[m]);                            \
      const h2v v0 = h2v{v.s0, v.s1}, v1 = h2v{v.s2, v.s3};                 \
      const h2v v2 = h2v{v.s4, v.s5}, v3 = h2v{v.s6, v.s7};                 \
      float& br = (m & 3) == 0 ? ahr0 : (m & 3) == 1 ? ahr1                 \
                : (m & 3) == 2 ? ahr2 : ahr3;                               \
      float& bz = (m & 3) == 0 ? ahz0 : (m & 3) == 1 ? ahz1                 \
                : (m & 3) == 2 ? ahz2 : ahz3;                               \
      float& bq = (m & 3) == 0 ? ahn0 : (m & 3) == 1 ? ahn1                 \
                : (m & 3) == 2 ? ahn2 : ahn3;                               \
      br = fdot2(v0, ash2(whr_i[4 * m + 0]), br);                           \
      br = fdot2(v1, ash2(whr_i[4 * m + 1]), br);                           \
      br = fdot2(v2, ash2(whr_i[4 * m + 2]), br);                           \
      br = fdot2(v3, ash2(whr_i[4 * m + 3]), br);                           \
      bz = fdot2(v0, ash2(whz_i[4 * m + 0]), bz);                           \
      bz = fdot2(v1, ash2(whz_i[4 * m + 1]), bz);                           \
      bz = fdot2(v2, ash2(whz_i[4 * m + 2]), bz);                           \
      bz = fdot2(v3, ash2(whz_i[4 * m + 3]), bz);                           \
      bq = fdot2(v0, ash2(whn_i[4 * m + 0]), bq);                           \
      bq = fdot2(v1, ash2(whn_i[4 * m + 1]), bq);                           \
      bq = fdot2(v2, ash2(whn_i[4 * m + 2]), bq);                           \
      bq = fdot2(v3, ash2(whn_i[4 * m + 3]), bq);                           \
    }                                                                       \
    /* 1-hop pair reduce (DPP), then gate tail */                           \
    float pr = pair_sum(cxr + ((ahr0 + ahr1) + (ahr2 + ahr3)));             \
    float pz = pair_sum(cxz + ((ahz0 + ahz1) + (ahz2 + ahz3)));             \
    float xnv = pair_sum(cxn);                                              \
    float hnv = pair_sum((ahn0 + ahn1) + (ahn2 + ahn3));                    \
    /* x-dot for t+1: independent -> fills the tail/write/barrier window */ \
    XDOT(((P) + 1) & 3, pxr, pxz, pxn)                                      \
    const float rg = FRCP(1.0f + __expf(-pr));                              \
    const float zg = FRCP(1.0f + __expf(-pz));                              \
    const float na = xnv + rg * hnv;                                        \
    const float ng = 1.0f - 2.0f * FRCP(__expf(2.0f * na) + 1.0f);          \
    const float hnew = zg * (h_old - ng) + ng;                              \
    h_old = hnew;                                                           \
    if (p == 0) {                                                           \
      h_lds[((P) + 1) & 1][g] = (_Float16)hnew;                             \
      *outp = hnew;                                                         \
    }                                                                       \
    outp += BB * HH;                                                        \
    step_barrier();                                                         \
  }

  for (int tbase = 0; tbase < TT; tbase += 4) {
    PINS();
    STEP(0, xv0)
    STEP(1, xv1)
    STEP(2, xv2)
    STEP(3, xv3)
  }
#undef STEP
#undef XDOT
}

extern "C" void kernel_launch(void* const* d_in, const int* in_sizes, int n_in,
                              void* d_out, int out_size, void* d_ws, size_t ws_size,
                              hipStream_t stream) {
  const float* x    = (const float*)d_in[0];
  const float* Wi   = (const float*)d_in[1];
  const float* bi   = (const float*)d_in[2];
  const float* Whrz = (const float*)d_in[3];
  const float* Whn  = (const float*)d_in[4];
  const float* bn   = (const float*)d_in[5];
  float* out = (float*)d_out;

  gru_scan_kernel<<<dim3(BB), dim3(NT), 0, stream>>>(
      x, Wi, bi, Whrz, Whn, bn, out);
}